// Round 1
// baseline (129.412 us; speedup 1.0000x reference)
//
#include <hip/hip_runtime.h>

typedef short bf16x8 __attribute__((ext_vector_type(8)));
typedef short short4v __attribute__((ext_vector_type(4)));
typedef float f32x4 __attribute__((ext_vector_type(4)));

__device__ __forceinline__ unsigned short f2bf(float f) {
  union { float f; unsigned u; } c; c.f = f;
  unsigned u = c.u;
  u += 0x7FFFu + ((u >> 16) & 1u);   // RNE
  return (unsigned short)(u >> 16);
}
__device__ __forceinline__ float bf2f(unsigned short h) {
  union { unsigned u; float f; } c; c.u = ((unsigned)h) << 16;
  return c.f;
}
__device__ __forceinline__ void gload16(const void* g, void* l) {
  __builtin_amdgcn_global_load_lds((const __attribute__((address_space(1))) void*)g,
                                   (__attribute__((address_space(3))) void*)l, 16, 0, 0);
}
__device__ __forceinline__ float sigm(float x) { return 1.0f / (1.0f + __expf(-x)); }
__device__ __forceinline__ float tanha(float x) { return 1.0f - 2.0f / (1.0f + __expf(2.0f * x)); }

// ---------------- setup kernels (permuted bf16 copies) ----------------

// Wt[n][k] = W[k][n], n<256, k<1024
__global__ __launch_bounds__(256) void s1_wt(const float* __restrict__ W, unsigned short* __restrict__ Wt) {
  int idx = blockIdx.x * 256 + threadIdx.x;
  if (idx >= 256 * 1024) return;
  int n = idx >> 10, k = idx & 1023;
  Wt[idx] = f2bf(W[k * 256 + n]);
}

// Ut[col][i] = Uhat[i][col]; col = j*192 + off_v + r; nonzero rows i in group (j+v)%4
__global__ __launch_bounds__(256) void s2_ut(const float* __restrict__ U, const float* __restrict__ UU,
                                             const float* __restrict__ UUU, const float* __restrict__ UUUU,
                                             unsigned short* __restrict__ Ut) {
  int idx = blockIdx.x * 256 + threadIdx.x;
  if (idx >= 768 * 1024) return;
  int col = idx >> 10, i = idx & 1023;
  int j = col / 192, cin = col % 192;
  int v, off, rv; const float* M;
  if (cin < 64)       { v = 0; off = 0;   rv = 64; M = U; }
  else if (cin < 128) { v = 1; off = 64;  rv = 64; M = UU; }
  else if (cin < 160) { v = 2; off = 128; rv = 32; M = UUU; }
  else                { v = 3; off = 160; rv = 32; M = UUUU; }
  int r = cin - off;
  int gsrc = (j + v) & 3;
  float val = 0.0f;
  if ((i >> 8) == gsrc) val = M[(j * 256 + (i & 255)) * rv + r];
  Ut[idx] = f2bf(val);
}

// Bt[j][n][k]: n = p*256+c (4 planes), k: [0,256)=Wcat, [256,512)=Wcat dup (lo-pass), [512,704)=V rows
__global__ __launch_bounds__(256) void s3_bt(
    const float* __restrict__ W1, const float* __restrict__ W2, const float* __restrict__ W3,
    const float* __restrict__ A1, const float* __restrict__ A2, const float* __restrict__ A3,
    const float* __restrict__ B1, const float* __restrict__ B2, const float* __restrict__ B3,
    const float* __restrict__ C1, const float* __restrict__ C2, const float* __restrict__ C3,
    const float* __restrict__ D1, const float* __restrict__ D2, const float* __restrict__ D3,
    unsigned short* __restrict__ Bt) {
  int idx = blockIdx.x * 256 + threadIdx.x;
  const int TOT = 4 * 1024 * 704;
  if (idx >= TOT) return;
  int j = idx / (1024 * 704);
  int rem = idx - j * (1024 * 704);
  int n = rem / 704, k = rem - n * 704;
  int p = n >> 8, c = n & 255;
  float val = 0.0f;
  if (k < 512) {
    int kk = k & 255;
    if (p == 0)      val = W1[kk * 1024 + j * 256 + c];
    else if (p == 1) val = W2[kk * 1024 + j * 256 + c];
    else if (p == 2) val = W3[kk * 1024 + j * 256 + c];
    // p==3: zero (u3-sum plane has no xw contribution)
  } else if (p != 2) {   // p==2 (w3 plane) has no T contribution
    int k2 = k - 512;
    int v, off, rv;
    if (k2 < 64)       { v = 0; off = 0;   rv = 64; }
    else if (k2 < 128) { v = 1; off = 64;  rv = 64; }
    else if (k2 < 160) { v = 2; off = 128; rv = 32; }
    else               { v = 3; off = 160; rv = 32; }
    int r = k2 - off;
    int pp = (p == 3) ? 2 : p;  // plane0->proj1, plane1->proj2, plane3->proj3
    const float* M;
    if (v == 0)      M = (pp == 0) ? A1 : (pp == 1) ? A2 : A3;
    else if (v == 1) M = (pp == 0) ? B1 : (pp == 1) ? B2 : B3;
    else if (v == 2) M = (pp == 0) ? C1 : (pp == 1) ? C2 : C3;
    else             M = (pp == 0) ? D1 : (pp == 1) ? D2 : D3;
    val = M[(j * rv + r) * 256 + c];
  }
  Bt[idx] = f2bf(val);
}

// ---------------- G1: xw = x @ W, 2-pass (x hi/lo), output hi/lo bf16 -> Abuf[:,0:512]
__global__ __launch_bounds__(256) void g1_xw(const float* __restrict__ x,
                                             const unsigned short* __restrict__ Wt,
                                             unsigned short* __restrict__ Abuf) {
  __shared__ unsigned short lAhi[64 * 64];
  __shared__ unsigned short lAlo[64 * 64];
  __shared__ unsigned short lB[64 * 64];
  const int tid = threadIdx.x;
  const int lane = tid & 63, wid = tid >> 6;
  const int mb = blockIdx.x, nb = blockIdx.y;
  const int wm = wid >> 1, wn = wid & 1;
  f32x4 acc[2][2] = {};
  char* lAhiB = (char*)lAhi;
  char* lAloB = (char*)lAlo;
  char* lBB = (char*)lB;
  for (int kt = 0; kt < 16; ++kt) {
#pragma unroll
    for (int q = 0; q < 4; ++q) {
      int i = q * 256 + tid;
      int row = i >> 4, f4c = i & 15;
      const float* src = x + (size_t)(mb * 64 + row) * 1024 + kt * 64 + f4c * 4;
      float4 v = *(const float4*)src;
      unsigned short h0 = f2bf(v.x), h1 = f2bf(v.y), h2 = f2bf(v.z), h3 = f2bf(v.w);
      unsigned short l0 = f2bf(v.x - bf2f(h0)), l1 = f2bf(v.y - bf2f(h1));
      unsigned short l2 = f2bf(v.z - bf2f(h2)), l3 = f2bf(v.w - bf2f(h3));
      int ba = row * 128 + ((f4c * 8) ^ ((row & 7) << 4));
      short4v hv = { (short)h0, (short)h1, (short)h2, (short)h3 };
      short4v lv = { (short)l0, (short)l1, (short)l2, (short)l3 };
      *(short4v*)(lAhiB + ba) = hv;
      *(short4v*)(lAloB + ba) = lv;
    }
#pragma unroll
    for (int it = 0; it < 2; ++it) {
      int nloc = wid * 16 + it * 8 + (lane >> 3);
      const char* src = (const char*)(Wt + (size_t)(nb * 64 + nloc) * 1024 + kt * 64)
                        + (((lane & 7) * 16) ^ ((nloc & 7) << 4));
      gload16(src, lBB + (wid * 16 + it * 8) * 128);
    }
    __syncthreads();
#pragma unroll
    for (int ks = 0; ks < 2; ++ks) {
      bf16x8 ah[2], al[2], b[2];
#pragma unroll
      for (int mf = 0; mf < 2; ++mf) {
        int mloc = wm * 32 + mf * 16 + (lane & 15);
        int ka = (ks * 64 + (lane >> 4) * 16) ^ ((mloc & 7) << 4);
        ah[mf] = *(const bf16x8*)(lAhiB + mloc * 128 + ka);
        al[mf] = *(const bf16x8*)(lAloB + mloc * 128 + ka);
      }
#pragma unroll
      for (int nf = 0; nf < 2; ++nf) {
        int nloc = wn * 32 + nf * 16 + (lane & 15);
        int kb = (ks * 64 + (lane >> 4) * 16) ^ ((nloc & 7) << 4);
        b[nf] = *(const bf16x8*)(lBB + nloc * 128 + kb);
      }
#pragma unroll
      for (int mf = 0; mf < 2; ++mf)
#pragma unroll
        for (int nf = 0; nf < 2; ++nf) {
          acc[mf][nf] = __builtin_amdgcn_mfma_f32_16x16x32_bf16(ah[mf], b[nf], acc[mf][nf], 0, 0, 0);
          acc[mf][nf] = __builtin_amdgcn_mfma_f32_16x16x32_bf16(al[mf], b[nf], acc[mf][nf], 0, 0, 0);
        }
    }
    __syncthreads();
  }
#pragma unroll
  for (int mf = 0; mf < 2; ++mf)
#pragma unroll
    for (int nf = 0; nf < 2; ++nf)
#pragma unroll
      for (int r = 0; r < 4; ++r) {
        int row = mb * 64 + wm * 32 + mf * 16 + (lane >> 4) * 4 + r;
        int col = nb * 64 + wn * 32 + nf * 16 + (lane & 15);
        float val = acc[mf][nf][r];
        unsigned short hi = f2bf(val);
        unsigned short lo = f2bf(val - bf2f(hi));
        Abuf[(size_t)row * 1280 + col] = hi;
        Abuf[(size_t)row * 1280 + 256 + col] = lo;
      }
}

// ---------------- G2: T = h @ Uhat -> Abuf[:,512:1280]
__global__ __launch_bounds__(256) void g2_t(const float* __restrict__ h,
                                            const unsigned short* __restrict__ Ut,
                                            unsigned short* __restrict__ Abuf) {
  __shared__ unsigned short lA[64 * 64];
  __shared__ unsigned short lB[128 * 64];
  const int tid = threadIdx.x;
  const int lane = tid & 63, wid = tid >> 6;
  const int mb = blockIdx.x, nb = blockIdx.y;
  const int wm = wid >> 1, wn = wid & 1;
  f32x4 acc[2][4] = {};
  char* lAB = (char*)lA;
  char* lBB = (char*)lB;
  for (int kt = 0; kt < 16; ++kt) {
#pragma unroll
    for (int q = 0; q < 4; ++q) {
      int i = q * 256 + tid;
      int row = i >> 4, f4c = i & 15;
      const float* src = h + (size_t)(mb * 64 + row) * 1024 + kt * 64 + f4c * 4;
      float4 v = *(const float4*)src;
      short4v hv = { (short)f2bf(v.x), (short)f2bf(v.y), (short)f2bf(v.z), (short)f2bf(v.w) };
      int ba = row * 128 + ((f4c * 8) ^ ((row & 7) << 4));
      *(short4v*)(lAB + ba) = hv;
    }
#pragma unroll
    for (int it = 0; it < 4; ++it) {
      int nloc = wid * 32 + it * 8 + (lane >> 3);
      const char* src = (const char*)(Ut + (size_t)(nb * 128 + nloc) * 1024 + kt * 64)
                        + (((lane & 7) * 16) ^ ((nloc & 7) << 4));
      gload16(src, lBB + (wid * 32 + it * 8) * 128);
    }
    __syncthreads();
#pragma unroll
    for (int ks = 0; ks < 2; ++ks) {
      bf16x8 a[2], b[4];
#pragma unroll
      for (int mf = 0; mf < 2; ++mf) {
        int mloc = wm * 32 + mf * 16 + (lane & 15);
        int ka = (ks * 64 + (lane >> 4) * 16) ^ ((mloc & 7) << 4);
        a[mf] = *(const bf16x8*)(lAB + mloc * 128 + ka);
      }
#pragma unroll
      for (int nf = 0; nf < 4; ++nf) {
        int nloc = wn * 64 + nf * 16 + (lane & 15);
        int kb = (ks * 64 + (lane >> 4) * 16) ^ ((nloc & 7) << 4);
        b[nf] = *(const bf16x8*)(lBB + nloc * 128 + kb);
      }
#pragma unroll
      for (int mf = 0; mf < 2; ++mf)
#pragma unroll
        for (int nf = 0; nf < 4; ++nf)
          acc[mf][nf] = __builtin_amdgcn_mfma_f32_16x16x32_bf16(a[mf], b[nf], acc[mf][nf], 0, 0, 0);
    }
    __syncthreads();
  }
#pragma unroll
  for (int mf = 0; mf < 2; ++mf)
#pragma unroll
    for (int nf = 0; nf < 4; ++nf)
#pragma unroll
      for (int r = 0; r < 4; ++r) {
        int row = mb * 64 + wm * 32 + mf * 16 + (lane >> 4) * 4 + r;
        int col = nb * 128 + wn * 64 + nf * 16 + (lane & 15);
        Abuf[(size_t)row * 1280 + 512 + col] = f2bf(acc[mf][nf][r]);
      }
}

// ---------------- G3: per-group fused GEMM + GRU elementwise epilogue
// BM=128, BN = 4 planes x 32 cols, K = 704 (8 xw tiles + 3 T tiles)
__global__ __launch_bounds__(256) void g3_main(const unsigned short* __restrict__ Abuf,
                                               const unsigned short* __restrict__ Bt,
                                               const float* __restrict__ h,
                                               const float* __restrict__ bias_r,
                                               const float* __restrict__ bias_g,
                                               const float* __restrict__ bias_u,
                                               float* __restrict__ out) {
  __shared__ unsigned short lA[128 * 64];
  __shared__ unsigned short lB[128 * 64];
  const int tid = threadIdx.x;
  const int lane = tid & 63, wid = tid >> 6;
  const int mb = blockIdx.x, nb = blockIdx.y, j = blockIdx.z;
  const int wm = wid >> 1, wn = wid & 1;
  f32x4 acc[4][4] = {};
  char* lAB = (char*)lA;
  char* lBB = (char*)lB;
  const unsigned short* BtJ = Bt + (size_t)j * 1024 * 704;
  for (int kt = 0; kt < 11; ++kt) {
    int colb = (kt < 8) ? kt * 64 : 512 + j * 192 + (kt - 8) * 64;
#pragma unroll
    for (int it = 0; it < 4; ++it) {
      int mloc = wid * 32 + it * 8 + (lane >> 3);
      const char* src = (const char*)(Abuf + (size_t)(mb * 128 + mloc) * 1280 + colb)
                        + (((lane & 7) * 16) ^ ((mloc & 7) << 4));
      gload16(src, lAB + (wid * 32 + it * 8) * 128);
    }
#pragma unroll
    for (int it = 0; it < 4; ++it) {
      int nloc = wid * 32 + it * 8 + (lane >> 3);
      int cb2 = (nloc >> 6) & 1, p = (nloc >> 4) & 3, c16 = nloc & 15;
      int rowsrc = p * 256 + nb * 32 + cb2 * 16 + c16;
      const char* src = (const char*)(BtJ + (size_t)rowsrc * 704 + kt * 64)
                        + (((lane & 7) * 16) ^ ((nloc & 7) << 4));
      gload16(src, lBB + (wid * 32 + it * 8) * 128);
    }
    __syncthreads();
    bool isT = (kt >= 8);
#pragma unroll
    for (int ks = 0; ks < 2; ++ks) {
      bf16x8 a[4];
#pragma unroll
      for (int mf = 0; mf < 4; ++mf) {
        int mloc = wm * 64 + mf * 16 + (lane & 15);
        int ka = (ks * 64 + (lane >> 4) * 16) ^ ((mloc & 7) << 4);
        a[mf] = *(const bf16x8*)(lAB + mloc * 128 + ka);
      }
#pragma unroll
      for (int p = 0; p < 4; ++p) {
        bool skip = (p == 2) ? isT : ((p == 3) ? !isT : false);
        if (!skip) {
          int nloc = wn * 64 + p * 16 + (lane & 15);
          int kb = (ks * 64 + (lane >> 4) * 16) ^ ((nloc & 7) << 4);
          bf16x8 b = *(const bf16x8*)(lBB + nloc * 128 + kb);
#pragma unroll
          for (int mf = 0; mf < 4; ++mf)
            acc[mf][p] = __builtin_amdgcn_mfma_f32_16x16x32_bf16(a[mf], b, acc[mf][p], 0, 0, 0);
        }
      }
    }
    __syncthreads();
  }
  // fused GRU epilogue
  int cg = j * 256 + nb * 32 + wn * 16 + (lane & 15);
  float br = bias_r[cg], bg = bias_g[cg], bu = bias_u[cg];
#pragma unroll
  for (int mf = 0; mf < 4; ++mf)
#pragma unroll
    for (int r = 0; r < 4; ++r) {
      int row = mb * 128 + wm * 64 + mf * 16 + (lane >> 4) * 4 + r;
      float p0 = acc[mf][0][r], p1 = acc[mf][1][r];
      float p2 = acc[mf][2][r], p3 = acc[mf][3][r];
      float rr = sigm(p0 + br);
      float zz = sigm(p1 + bg);
      float ct = tanha(p2 + rr * p3 + bu);
      float hv = h[(size_t)row * 1024 + cg];
      out[(size_t)row * 1024 + cg] = zz * hv + (1.0f - zz) * ct;
    }
}

extern "C" void kernel_launch(void* const* d_in, const int* in_sizes, int n_in,
                              void* d_out, int out_size, void* d_ws, size_t ws_size,
                              hipStream_t stream) {
  const float* x   = (const float*)d_in[0];
  const float* h   = (const float*)d_in[1];
  const float* W   = (const float*)d_in[2];
  const float* W1  = (const float*)d_in[3];
  const float* W2  = (const float*)d_in[4];
  const float* W3  = (const float*)d_in[5];
  const float* U   = (const float*)d_in[6];
  const float* U1  = (const float*)d_in[7];
  const float* U2  = (const float*)d_in[8];
  const float* U3  = (const float*)d_in[9];
  const float* UU   = (const float*)d_in[10];
  const float* UU1  = (const float*)d_in[11];
  const float* UU2  = (const float*)d_in[12];
  const float* UU3  = (const float*)d_in[13];
  const float* UUU   = (const float*)d_in[14];
  const float* UUU1  = (const float*)d_in[15];
  const float* UUU2  = (const float*)d_in[16];
  const float* UUU3  = (const float*)d_in[17];
  const float* UUUU   = (const float*)d_in[18];
  const float* UUUU1  = (const float*)d_in[19];
  const float* UUUU2  = (const float*)d_in[20];
  const float* UUUU3  = (const float*)d_in[21];
  const float* bias_r = (const float*)d_in[22];
  const float* bias_g = (const float*)d_in[23];
  const float* bias_u = (const float*)d_in[24];

  char* ws = (char*)d_ws;
  unsigned short* Abuf = (unsigned short*)(ws);              // 8192x1280 bf16 = 20,971,520 B
  unsigned short* Wt   = (unsigned short*)(ws + 20971520);   // 256x1024 bf16  =    524,288 B
  unsigned short* Ut   = (unsigned short*)(ws + 21495808);   // 768x1024 bf16  =  1,572,864 B
  unsigned short* Bt   = (unsigned short*)(ws + 23068672);   // 4x1024x704 bf16=  5,767,168 B
  float* out = (float*)d_out;

  s1_wt<<<1024, 256, 0, stream>>>(W, Wt);
  s2_ut<<<3072, 256, 0, stream>>>(U, UU, UUU, UUUU, Ut);
  s3_bt<<<11264, 256, 0, stream>>>(W1, W2, W3, U1, U2, U3, UU1, UU2, UU3,
                                   UUU1, UUU2, UUU3, UUUU1, UUUU2, UUUU3, Bt);
  g1_xw<<<dim3(128, 4), 256, 0, stream>>>(x, Wt, Abuf);
  g2_t<<<dim3(128, 6), 256, 0, stream>>>(h, Ut, Abuf);
  g3_main<<<dim3(64, 8, 4), 256, 0, stream>>>(Abuf, Bt, h, bias_r, bias_g, bias_u, out);
}